// Round 18
// baseline (302.629 us; speedup 1.0000x reference)
//
#include <hip/hip_runtime.h>

#define N_SRC   100000
#define N_TGT   50000
#define N_EDGES 1000000
#define NEG     0.2
#define NXCD    8
#define TPART   (N_TGT / NXCD)   // 6250
#define SPART   (N_SRC / NXCD)   // 12500

#define GBLK_S  1563             // ceil(N_SRC/64)
#define GBLK_T  782              // ceil(N_TGT/64)
#define GBLK    (GBLK_S + GBLK_T)          // 2345 gemm blocks
#define NHIST   640              // hist blocks, grid-stride, dispatched FIRST

// ===========================================================================
// R18: gather ILP 4->8 (MLP underfilled at 4); NT loads in scatter (pack/nbhd
// are stream-once per XCD — caching them evicts srt write-combining lines)
// and in hist (rows/cols read exactly once). Base = R17 (282.6 us).
// ===========================================================================

// ---------------------------------------------------------------------------
#define XS2 65
__global__ __launch_bounds__(256) void fused_gemm_hist(
    const float* __restrict__ x_source, const float* __restrict__ x_target,
    const float* __restrict__ w_s, const float* __restrict__ w_t,
    const float* __restrict__ att,
    float* __restrict__ s_msg, float* __restrict__ t_msg,
    double* __restrict__ es_d, double* __restrict__ et_d,
    const int* __restrict__ rows, const int* __restrict__ cols,
    int* __restrict__ cnt_r, int* __restrict__ cnt_c,
    unsigned* __restrict__ packT, unsigned* __restrict__ packC)
{
    __shared__ float xs[64 * XS2];         // 16.6 KB
    __shared__ double eds[4][64];          //  2.0 KB
    const int tid = threadIdx.x;

    if (blockIdx.x < NHIST) {
        // ------- hist branch: dispatched first, grid-stride, 4x unrolled ------
        const int S = NHIST * 256;
        int i = blockIdx.x * 256 + tid;
        for (; i + 3 * S < N_EDGES; i += 4 * S) {
            const unsigned r0 = (unsigned)__builtin_nontemporal_load(&rows[i]);
            const unsigned c0_= (unsigned)__builtin_nontemporal_load(&cols[i]);
            const unsigned r1 = (unsigned)__builtin_nontemporal_load(&rows[i + S]);
            const unsigned c1_= (unsigned)__builtin_nontemporal_load(&cols[i + S]);
            const unsigned r2 = (unsigned)__builtin_nontemporal_load(&rows[i + 2 * S]);
            const unsigned c2_= (unsigned)__builtin_nontemporal_load(&cols[i + 2 * S]);
            const unsigned r3 = (unsigned)__builtin_nontemporal_load(&rows[i + 3 * S]);
            const unsigned c3_= (unsigned)__builtin_nontemporal_load(&cols[i + 3 * S]);
            const unsigned kr0 = atomicAdd(&cnt_r[r0], 1);
            const unsigned kc0 = atomicAdd(&cnt_c[c0_], 1);
            const unsigned kr1 = atomicAdd(&cnt_r[r1], 1);
            const unsigned kc1 = atomicAdd(&cnt_c[c1_], 1);
            const unsigned kr2 = atomicAdd(&cnt_r[r2], 1);
            const unsigned kc2 = atomicAdd(&cnt_c[c2_], 1);
            const unsigned kr3 = atomicAdd(&cnt_r[r3], 1);
            const unsigned kc3 = atomicAdd(&cnt_c[c3_], 1);
            packT[i]         = r0 | (kr0 << 16); packC[i]         = c0_ | (kc0 << 17);
            packT[i + S]     = r1 | (kr1 << 16); packC[i + S]     = c1_ | (kc1 << 17);
            packT[i + 2 * S] = r2 | (kr2 << 16); packC[i + 2 * S] = c2_ | (kc2 << 17);
            packT[i + 3 * S] = r3 | (kr3 << 16); packC[i + 3 * S] = c3_ | (kc3 << 17);
        }
        for (; i < N_EDGES; i += S) {
            const unsigned r = rows[i], c = cols[i];
            packT[i] = r | ((unsigned)atomicAdd(&cnt_r[r], 1) << 16);
            packC[i] = c | ((unsigned)atomicAdd(&cnt_c[c], 1) << 17);
        }
        return;
    }

    // ---------------- gemm branch ----------------
    const int gi = blockIdx.x - NHIST;

    const float* x; const float* w; int att_off, nrows, bblk;
    float* msg; double* evec;
    if (gi < GBLK_S) { x = x_source; w = w_s; att_off = 0;  nrows = N_SRC;
                       msg = s_msg;  evec = es_d; bblk = gi; }
    else             { x = x_target; w = w_t; att_off = 64; nrows = N_TGT;
                       msg = t_msg;  evec = et_d; bblk = gi - GBLK_S; }

    const int lane = tid & 63;
    const int part = tid >> 6;
    const int c0   = __builtin_amdgcn_readfirstlane(part << 4);
    const int row0 = bblk * 64;
    const int row  = row0 + lane;
    const bool act = row < nrows;

    float acc[16];
    #pragma unroll
    for (int c = 0; c < 16; ++c) acc[c] = 0.f;

    const int xbase = lane * XS2;

    // ---- stage half0 ----
    #pragma unroll
    for (int it = 0; it < 4; ++it) {
        const int fid = tid + it * 256;
        const int r = fid >> 4, q = fid & 15;
        if (row0 + r < nrows) {
            const float4 v = *(const float4*)(x + (size_t)(row0 + r) * 128 + 4 * q);
            float* d = &xs[r * XS2 + 4 * q];
            d[0] = v.x; d[1] = v.y; d[2] = v.z; d[3] = v.w;
        }
    }
    __syncthreads();

    // ---- issue half1 loads (in flight during half0 compute) ----
    float4 pre[4];
    #pragma unroll
    for (int it = 0; it < 4; ++it) {
        const int fid = tid + it * 256;
        const int r = fid >> 4, q = fid & 15;
        pre[it] = (row0 + r < nrows)
            ? *(const float4*)(x + (size_t)(row0 + r) * 128 + 64 + 4 * q)
            : make_float4(0.f, 0.f, 0.f, 0.f);
    }

    // ---- compute half0 ----
    for (int kc = 0; kc < 64; kc += 16) {
        #pragma unroll
        for (int kk = 0; kk < 16; ++kk) {
            const float xk = xs[xbase + kc + kk];
            const float* wr = w + (size_t)(kc + kk) * 64 + c0;   // scalar addr
            #pragma unroll
            for (int c = 0; c < 16; ++c)
                acc[c] = fmaf(xk, wr[c], acc[c]);
        }
    }
    __syncthreads();

    // ---- write half1 to LDS ----
    #pragma unroll
    for (int it = 0; it < 4; ++it) {
        const int fid = tid + it * 256;
        const int r = fid >> 4, q = fid & 15;
        float* d = &xs[r * XS2 + 4 * q];
        d[0] = pre[it].x; d[1] = pre[it].y; d[2] = pre[it].z; d[3] = pre[it].w;
    }
    __syncthreads();

    // ---- compute half1 ----
    for (int kc = 0; kc < 64; kc += 16) {
        #pragma unroll
        for (int kk = 0; kk < 16; ++kk) {
            const float xk = xs[xbase + kc + kk];
            const float* wr = w + (size_t)(64 + kc + kk) * 64 + c0;
            #pragma unroll
            for (int c = 0; c < 16; ++c)
                acc[c] = fmaf(xk, wr[c], acc[c]);
        }
    }

    double e = 0.0;
    #pragma unroll
    for (int c = 0; c < 16; ++c)
        e += (double)acc[c] * (double)att[att_off + c0 + c];
    eds[part][lane] = e;
    __syncthreads();
    if (part == 0 && act)
        evec[row] = eds[0][lane] + eds[1][lane] + eds[2][lane] + eds[3][lane];

    if (act) {
        float* mo = msg + (size_t)row * 64 + c0;
        #pragma unroll
        for (int q = 0; q < 4; ++q)
            *(float4*)(mo + 4 * q) = *(float4*)(acc + 4 * q);
    }
}

// ---------------------------------------------------------------------------
// Exclusive scan, tiled + coalesced. block 0 -> rows (N_TGT), 1 -> cols (N_SRC).
// ---------------------------------------------------------------------------
__global__ __launch_bounds__(1024) void scan_two(
    const int* __restrict__ cnt_r, const int* __restrict__ cnt_c,
    int* __restrict__ ptr_r, int* __restrict__ ptr_c)
{
    const int n    = blockIdx.x ? N_SRC : N_TGT;
    const int* cnt = blockIdx.x ? cnt_c : cnt_r;
    int* ptr       = blockIdx.x ? ptr_c : ptr_r;
    const int tid  = threadIdx.x;
    const int lane = tid & 63, wid = tid >> 6;

    __shared__ int wsum[16];
    __shared__ int s_carry;
    if (tid == 0) s_carry = 0;
    __syncthreads();

    for (int base = 0; base < n; base += 4096) {
        const int idx = base + tid * 4;
        int4 v = make_int4(0, 0, 0, 0);
        if (idx + 3 < n) {
            v = *(const int4*)(cnt + idx);
        } else if (idx < n) {
            v.x = cnt[idx];
            if (idx + 1 < n) v.y = cnt[idx + 1];
            if (idx + 2 < n) v.z = cnt[idx + 2];
        }
        const int s = v.x + v.y + v.z + v.w;

        int p = s;
        #pragma unroll
        for (int d = 1; d < 64; d <<= 1) {
            int t = __shfl_up(p, d);
            if (lane >= d) p += t;
        }
        if (lane == 63) wsum[wid] = p;
        __syncthreads();
        if (tid == 0) {
            int a = 0;
            #pragma unroll
            for (int i = 0; i < 16; ++i) { int t = wsum[i]; wsum[i] = a; a += t; }
        }
        __syncthreads();

        int run = s_carry + wsum[wid] + (p - s);
        if (idx     < n) ptr[idx]     = run; run += v.x;
        if (idx + 1 < n) ptr[idx + 1] = run; run += v.y;
        if (idx + 2 < n) ptr[idx + 2] = run; run += v.z;
        if (idx + 3 < n) ptr[idx + 3] = run; run += v.w;

        __syncthreads();
        if (tid == 1023) s_carry = run;
        __syncthreads();
    }
    if (tid == 0) ptr[n] = s_carry;
}

// ---------------------------------------------------------------------------
// Scatter, XCD-partitioned (R8) + atomic-free (R12) + packed (R17) + NT
// streaming loads (R18): pack/nbhd lines are read once per XCD — keep L2
// free for srt write-combining.
// ---------------------------------------------------------------------------
__global__ __launch_bounds__(256) void scatter_part(
    const unsigned* __restrict__ packT, const unsigned* __restrict__ packC,
    const float* __restrict__ nbhd,
    const int* __restrict__ ptr_r, const int* __restrict__ ptr_c,
    unsigned long long* __restrict__ srtT, unsigned long long* __restrict__ srtS)
{
    const int xcd  = blockIdx.x & (NXCD - 1);
    const int ibx  = blockIdx.x >> 3;
    const int step = (gridDim.x >> 3) * blockDim.x;
    const unsigned lo_r = xcd * TPART, lo_c = xcd * SPART;

    for (int i = ibx * blockDim.x + threadIdx.x; i < N_EDGES; i += step) {
        const unsigned pT = __builtin_nontemporal_load(&packT[i]);
        const unsigned pC = __builtin_nontemporal_load(&packC[i]);
        const unsigned r = pT & 0xFFFFu,  kr = pT >> 16;
        const unsigned c = pC & 0x1FFFFu, kc = pC >> 17;
        const bool mr = (r - lo_r) < TPART;
        const bool mc = (c - lo_c) < SPART;
        if (!(mr | mc)) continue;
        const unsigned long long nb =
            (unsigned long long)(unsigned)__float_as_int(
                __builtin_nontemporal_load(&nbhd[i])) << 32;
        if (mr) srtT[ptr_r[r] + kr] = nb | c;
        if (mc) srtS[ptr_c[c] + kc] = nb | r;
    }
}

// ---------------------------------------------------------------------------
// Gather: one wave per output row, lane = feature. den f64 (cancelling sum);
// numerator f32; 8-deep load ILP (R18).
// ---------------------------------------------------------------------------
__global__ __launch_bounds__(256) void gather_both(
    const int2* __restrict__ srtT, const int* __restrict__ ptr_r,
    const float* __restrict__ s_msg, float* __restrict__ msg_tgt,
    const int2* __restrict__ srtS, const int* __restrict__ ptr_c,
    const float* __restrict__ t_msg, float* __restrict__ msg_src,
    const double* __restrict__ es_d, const double* __restrict__ et_d)
{
    const int gw   = (blockIdx.x * blockDim.x + threadIdx.x) >> 6;
    const int lane = threadIdx.x & 63;

    const int2* srt; const int* ptr; const float* min_; float* out;
    const double* other_d; double base; int row;
    if (gw < N_TGT) {
        srt = srtT; ptr = ptr_r; min_ = s_msg; out = msg_tgt;
        other_d = es_d; row = gw; base = et_d[row];
    } else {
        row = gw - N_TGT;
        if (row >= N_SRC) return;
        srt = srtS; ptr = ptr_c; min_ = t_msg; out = msg_src;
        other_d = et_d; base = es_d[row];
    }

    const int b = ptr[row], e = ptr[row + 1];
    double den = 0.0;
    float a0 = 0.f, a1 = 0.f, a2 = 0.f, a3 = 0.f;

    for (int j0 = b; j0 < e; j0 += 64) {
        const int m = e - j0;
        int oidx = 0; double v = 0.0; float wf = 0.f;
        if (lane < m) {
            const int2 pay = srt[j0 + lane];
            oidx = pay.x;
            const float nb = __int_as_float(pay.y);
            const double sv = base + other_d[oidx];
            v = (sv >= 0.0) ? sv : NEG * sv;
            wf = (float)(v * (double)nb);
        }
        den += v;

        const int cnt = m < 64 ? m : 64;
        int j = 0;
        for (; j + 7 < cnt; j += 8) {
            const int   c0_ = __shfl(oidx, j);     const float w0 = __shfl(wf, j);
            const int   c1_ = __shfl(oidx, j + 1); const float w1 = __shfl(wf, j + 1);
            const int   c2_ = __shfl(oidx, j + 2); const float w2 = __shfl(wf, j + 2);
            const int   c3_ = __shfl(oidx, j + 3); const float w3 = __shfl(wf, j + 3);
            const int   c4_ = __shfl(oidx, j + 4); const float w4 = __shfl(wf, j + 4);
            const int   c5_ = __shfl(oidx, j + 5); const float w5 = __shfl(wf, j + 5);
            const int   c6_ = __shfl(oidx, j + 6); const float w6 = __shfl(wf, j + 6);
            const int   c7_ = __shfl(oidx, j + 7); const float w7 = __shfl(wf, j + 7);
            const float m0 = min_[(size_t)c0_ * 64 + lane];
            const float m1 = min_[(size_t)c1_ * 64 + lane];
            const float m2 = min_[(size_t)c2_ * 64 + lane];
            const float m3 = min_[(size_t)c3_ * 64 + lane];
            const float m4 = min_[(size_t)c4_ * 64 + lane];
            const float m5 = min_[(size_t)c5_ * 64 + lane];
            const float m6 = min_[(size_t)c6_ * 64 + lane];
            const float m7 = min_[(size_t)c7_ * 64 + lane];
            a0 = fmaf(w0, m0, a0); a1 = fmaf(w1, m1, a1);
            a2 = fmaf(w2, m2, a2); a3 = fmaf(w3, m3, a3);
            a0 = fmaf(w4, m4, a0); a1 = fmaf(w5, m5, a1);
            a2 = fmaf(w6, m6, a2); a3 = fmaf(w7, m7, a3);
        }
        for (; j + 3 < cnt; j += 4) {
            const int   c0_ = __shfl(oidx, j);     const float w0 = __shfl(wf, j);
            const int   c1_ = __shfl(oidx, j + 1); const float w1 = __shfl(wf, j + 1);
            const int   c2_ = __shfl(oidx, j + 2); const float w2 = __shfl(wf, j + 2);
            const int   c3_ = __shfl(oidx, j + 3); const float w3 = __shfl(wf, j + 3);
            a0 = fmaf(w0, min_[(size_t)c0_ * 64 + lane], a0);
            a1 = fmaf(w1, min_[(size_t)c1_ * 64 + lane], a1);
            a2 = fmaf(w2, min_[(size_t)c2_ * 64 + lane], a2);
            a3 = fmaf(w3, min_[(size_t)c3_ * 64 + lane], a3);
        }
        for (; j < cnt; ++j) {
            const int   c = __shfl(oidx, j);
            const float w = __shfl(wf, j);
            a0 = fmaf(w, min_[(size_t)c * 64 + lane], a0);
        }
    }
    #pragma unroll
    for (int s = 32; s; s >>= 1) den += __shfl_xor(den, s);
    const double inv = (den != 0.0) ? 1.0 / den : 0.0;
    const double acc = (double)((a0 + a1) + (a2 + a3));
    out[(size_t)row * 64 + lane] = (float)(acc * inv);
}

// ===========================================================================
extern "C" void kernel_launch(void* const* d_in, const int* in_sizes, int n_in,
                              void* d_out, int out_size, void* d_ws, size_t ws_size,
                              hipStream_t stream)
{
    const float* x_source = (const float*)d_in[0];
    const float* x_target = (const float*)d_in[1];
    const float* w_s      = (const float*)d_in[2];
    const float* w_t      = (const float*)d_in[3];
    const float* att      = (const float*)d_in[4];
    const float* nbhd     = (const float*)d_in[5];
    const int*   rows     = (const int*)d_in[6];
    const int*   cols     = (const int*)d_in[7];

    float* out     = (float*)d_out;
    float* msg_src = out;                       // (N_SRC, 64)
    float* msg_tgt = out + (size_t)N_SRC * 64;  // (N_TGT, 64)

    char* ws = (char*)d_ws;
    // byte layout: total 65,400,016 B
    float*    s_msg  = (float*)   (ws + 0);           // 25,600,000
    float*    t_msg  = (float*)   (ws + 25600000);    // 12,800,000
    double*   es_d   = (double*)  (ws + 38400000);    //    800,000
    double*   et_d   = (double*)  (ws + 39200000);    //    400,000
    int*      cnt_r  = (int*)     (ws + 39600000);    //    200,000
    int*      cnt_c  = (int*)     (ws + 39800000);    //    400,000
    int*      ptr_r  = (int*)     (ws + 40200000);    //    200,004
    int*      ptr_c  = (int*)     (ws + 40400004);    //    400,004 (+8 pad)
    unsigned* packT  = (unsigned*)(ws + 40800016);    //  4,000,000
    unsigned* packC  = (unsigned*)(ws + 44800016);    //  4,000,000
    unsigned long long* srtT = (unsigned long long*)(ws + 48800016); // 8,000,000
    unsigned long long* srtS = (unsigned long long*)(ws + 56800016); // 8,000,000

    hipMemsetAsync(ws + 39600000, 0, 600000, stream);  // cnt_r + cnt_c

    fused_gemm_hist<<<NHIST + GBLK, 256, 0, stream>>>(
        x_source, x_target, w_s, w_t, att,
        s_msg, t_msg, es_d, et_d,
        rows, cols, cnt_r, cnt_c, packT, packC);

    scan_two<<<2, 1024, 0, stream>>>(cnt_r, cnt_c, ptr_r, ptr_c);
    scatter_part<<<2048, 256, 0, stream>>>(
        packT, packC, nbhd, ptr_r, ptr_c, srtT, srtS);

    gather_both<<<(N_TGT + N_SRC + 3) / 4, 256, 0, stream>>>(
        (const int2*)srtT, ptr_r, s_msg, msg_tgt,
        (const int2*)srtS, ptr_c, t_msg, msg_src, es_d, et_d);
}

// Round 19
// 279.864 us; speedup vs baseline: 1.0813x; 1.0813x over previous
//
#include <hip/hip_runtime.h>

#define N_SRC   100000
#define N_TGT   50000
#define N_EDGES 1000000
#define NEG     0.2
#define NXCD    8
#define TPART   (N_TGT / NXCD)   // 6250
#define SPART   (N_SRC / NXCD)   // 12500

#define GBLK_S  1563             // ceil(N_SRC/64)
#define GBLK_T  782              // ceil(N_TGT/64)
#define GBLK    (GBLK_S + GBLK_T)          // 2345 gemm blocks
#define NHIST   640              // hist blocks, grid-stride, dispatched FIRST

// ===========================================================================
// R19: attribution round. Revert R18's NT loads in scatter/hist (pack arrays
// are L2-hot from the producing kernel — NT forced ~96 MB to HBM, the +20 us
// regression); KEEP gather ILP-8 (mechanism-neutral, validated absmax 1024).
// Base structure = R17 (282.6 us best).
// ===========================================================================

// ---------------------------------------------------------------------------
#define XS2 65
__global__ __launch_bounds__(256) void fused_gemm_hist(
    const float* __restrict__ x_source, const float* __restrict__ x_target,
    const float* __restrict__ w_s, const float* __restrict__ w_t,
    const float* __restrict__ att,
    float* __restrict__ s_msg, float* __restrict__ t_msg,
    double* __restrict__ es_d, double* __restrict__ et_d,
    const int* __restrict__ rows, const int* __restrict__ cols,
    int* __restrict__ cnt_r, int* __restrict__ cnt_c,
    unsigned* __restrict__ packT, unsigned* __restrict__ packC)
{
    __shared__ float xs[64 * XS2];         // 16.6 KB
    __shared__ double eds[4][64];          //  2.0 KB
    const int tid = threadIdx.x;

    if (blockIdx.x < NHIST) {
        // ------- hist branch: dispatched first, grid-stride, 4x unrolled ------
        const int S = NHIST * 256;
        int i = blockIdx.x * 256 + tid;
        for (; i + 3 * S < N_EDGES; i += 4 * S) {
            const unsigned r0 = rows[i],         c0_ = cols[i];
            const unsigned r1 = rows[i + S],     c1_ = cols[i + S];
            const unsigned r2 = rows[i + 2 * S], c2_ = cols[i + 2 * S];
            const unsigned r3 = rows[i + 3 * S], c3_ = cols[i + 3 * S];
            const unsigned kr0 = atomicAdd(&cnt_r[r0], 1);
            const unsigned kc0 = atomicAdd(&cnt_c[c0_], 1);
            const unsigned kr1 = atomicAdd(&cnt_r[r1], 1);
            const unsigned kc1 = atomicAdd(&cnt_c[c1_], 1);
            const unsigned kr2 = atomicAdd(&cnt_r[r2], 1);
            const unsigned kc2 = atomicAdd(&cnt_c[c2_], 1);
            const unsigned kr3 = atomicAdd(&cnt_r[r3], 1);
            const unsigned kc3 = atomicAdd(&cnt_c[c3_], 1);
            packT[i]         = r0 | (kr0 << 16); packC[i]         = c0_ | (kc0 << 17);
            packT[i + S]     = r1 | (kr1 << 16); packC[i + S]     = c1_ | (kc1 << 17);
            packT[i + 2 * S] = r2 | (kr2 << 16); packC[i + 2 * S] = c2_ | (kc2 << 17);
            packT[i + 3 * S] = r3 | (kr3 << 16); packC[i + 3 * S] = c3_ | (kc3 << 17);
        }
        for (; i < N_EDGES; i += S) {
            const unsigned r = rows[i], c = cols[i];
            packT[i] = r | ((unsigned)atomicAdd(&cnt_r[r], 1) << 16);
            packC[i] = c | ((unsigned)atomicAdd(&cnt_c[c], 1) << 17);
        }
        return;
    }

    // ---------------- gemm branch ----------------
    const int gi = blockIdx.x - NHIST;

    const float* x; const float* w; int att_off, nrows, bblk;
    float* msg; double* evec;
    if (gi < GBLK_S) { x = x_source; w = w_s; att_off = 0;  nrows = N_SRC;
                       msg = s_msg;  evec = es_d; bblk = gi; }
    else             { x = x_target; w = w_t; att_off = 64; nrows = N_TGT;
                       msg = t_msg;  evec = et_d; bblk = gi - GBLK_S; }

    const int lane = tid & 63;
    const int part = tid >> 6;
    const int c0   = __builtin_amdgcn_readfirstlane(part << 4);
    const int row0 = bblk * 64;
    const int row  = row0 + lane;
    const bool act = row < nrows;

    float acc[16];
    #pragma unroll
    for (int c = 0; c < 16; ++c) acc[c] = 0.f;

    const int xbase = lane * XS2;

    // ---- stage half0 ----
    #pragma unroll
    for (int it = 0; it < 4; ++it) {
        const int fid = tid + it * 256;
        const int r = fid >> 4, q = fid & 15;
        if (row0 + r < nrows) {
            const float4 v = *(const float4*)(x + (size_t)(row0 + r) * 128 + 4 * q);
            float* d = &xs[r * XS2 + 4 * q];
            d[0] = v.x; d[1] = v.y; d[2] = v.z; d[3] = v.w;
        }
    }
    __syncthreads();

    // ---- issue half1 loads (in flight during half0 compute) ----
    float4 pre[4];
    #pragma unroll
    for (int it = 0; it < 4; ++it) {
        const int fid = tid + it * 256;
        const int r = fid >> 4, q = fid & 15;
        pre[it] = (row0 + r < nrows)
            ? *(const float4*)(x + (size_t)(row0 + r) * 128 + 64 + 4 * q)
            : make_float4(0.f, 0.f, 0.f, 0.f);
    }

    // ---- compute half0 ----
    for (int kc = 0; kc < 64; kc += 16) {
        #pragma unroll
        for (int kk = 0; kk < 16; ++kk) {
            const float xk = xs[xbase + kc + kk];
            const float* wr = w + (size_t)(kc + kk) * 64 + c0;   // scalar addr
            #pragma unroll
            for (int c = 0; c < 16; ++c)
                acc[c] = fmaf(xk, wr[c], acc[c]);
        }
    }
    __syncthreads();

    // ---- write half1 to LDS ----
    #pragma unroll
    for (int it = 0; it < 4; ++it) {
        const int fid = tid + it * 256;
        const int r = fid >> 4, q = fid & 15;
        float* d = &xs[r * XS2 + 4 * q];
        d[0] = pre[it].x; d[1] = pre[it].y; d[2] = pre[it].z; d[3] = pre[it].w;
    }
    __syncthreads();

    // ---- compute half1 ----
    for (int kc = 0; kc < 64; kc += 16) {
        #pragma unroll
        for (int kk = 0; kk < 16; ++kk) {
            const float xk = xs[xbase + kc + kk];
            const float* wr = w + (size_t)(64 + kc + kk) * 64 + c0;
            #pragma unroll
            for (int c = 0; c < 16; ++c)
                acc[c] = fmaf(xk, wr[c], acc[c]);
        }
    }

    double e = 0.0;
    #pragma unroll
    for (int c = 0; c < 16; ++c)
        e += (double)acc[c] * (double)att[att_off + c0 + c];
    eds[part][lane] = e;
    __syncthreads();
    if (part == 0 && act)
        evec[row] = eds[0][lane] + eds[1][lane] + eds[2][lane] + eds[3][lane];

    if (act) {
        float* mo = msg + (size_t)row * 64 + c0;
        #pragma unroll
        for (int q = 0; q < 4; ++q)
            *(float4*)(mo + 4 * q) = *(float4*)(acc + 4 * q);
    }
}

// ---------------------------------------------------------------------------
// Exclusive scan, tiled + coalesced. block 0 -> rows (N_TGT), 1 -> cols (N_SRC).
// ---------------------------------------------------------------------------
__global__ __launch_bounds__(1024) void scan_two(
    const int* __restrict__ cnt_r, const int* __restrict__ cnt_c,
    int* __restrict__ ptr_r, int* __restrict__ ptr_c)
{
    const int n    = blockIdx.x ? N_SRC : N_TGT;
    const int* cnt = blockIdx.x ? cnt_c : cnt_r;
    int* ptr       = blockIdx.x ? ptr_c : ptr_r;
    const int tid  = threadIdx.x;
    const int lane = tid & 63, wid = tid >> 6;

    __shared__ int wsum[16];
    __shared__ int s_carry;
    if (tid == 0) s_carry = 0;
    __syncthreads();

    for (int base = 0; base < n; base += 4096) {
        const int idx = base + tid * 4;
        int4 v = make_int4(0, 0, 0, 0);
        if (idx + 3 < n) {
            v = *(const int4*)(cnt + idx);
        } else if (idx < n) {
            v.x = cnt[idx];
            if (idx + 1 < n) v.y = cnt[idx + 1];
            if (idx + 2 < n) v.z = cnt[idx + 2];
        }
        const int s = v.x + v.y + v.z + v.w;

        int p = s;
        #pragma unroll
        for (int d = 1; d < 64; d <<= 1) {
            int t = __shfl_up(p, d);
            if (lane >= d) p += t;
        }
        if (lane == 63) wsum[wid] = p;
        __syncthreads();
        if (tid == 0) {
            int a = 0;
            #pragma unroll
            for (int i = 0; i < 16; ++i) { int t = wsum[i]; wsum[i] = a; a += t; }
        }
        __syncthreads();

        int run = s_carry + wsum[wid] + (p - s);
        if (idx     < n) ptr[idx]     = run; run += v.x;
        if (idx + 1 < n) ptr[idx + 1] = run; run += v.y;
        if (idx + 2 < n) ptr[idx + 2] = run; run += v.z;
        if (idx + 3 < n) ptr[idx + 3] = run; run += v.w;

        __syncthreads();
        if (tid == 1023) s_carry = run;
        __syncthreads();
    }
    if (tid == 0) ptr[n] = s_carry;
}

// ---------------------------------------------------------------------------
// Scatter, XCD-partitioned (R8) + atomic-free (R12) + packed (R17).
// Plain loads (R19: pack arrays are L2/L3-hot from the producer — NT was the
// R18 regression).
// ---------------------------------------------------------------------------
__global__ __launch_bounds__(256) void scatter_part(
    const unsigned* __restrict__ packT, const unsigned* __restrict__ packC,
    const float* __restrict__ nbhd,
    const int* __restrict__ ptr_r, const int* __restrict__ ptr_c,
    unsigned long long* __restrict__ srtT, unsigned long long* __restrict__ srtS)
{
    const int xcd  = blockIdx.x & (NXCD - 1);
    const int ibx  = blockIdx.x >> 3;
    const int step = (gridDim.x >> 3) * blockDim.x;
    const unsigned lo_r = xcd * TPART, lo_c = xcd * SPART;

    for (int i = ibx * blockDim.x + threadIdx.x; i < N_EDGES; i += step) {
        const unsigned pT = packT[i], pC = packC[i];
        const unsigned r = pT & 0xFFFFu,  kr = pT >> 16;
        const unsigned c = pC & 0x1FFFFu, kc = pC >> 17;
        const bool mr = (r - lo_r) < TPART;
        const bool mc = (c - lo_c) < SPART;
        if (!(mr | mc)) continue;
        const unsigned long long nb =
            (unsigned long long)(unsigned)__float_as_int(nbhd[i]) << 32;
        if (mr) srtT[ptr_r[r] + kr] = nb | c;
        if (mc) srtS[ptr_c[c] + kc] = nb | r;
    }
}

// ---------------------------------------------------------------------------
// Gather: one wave per output row, lane = feature. den f64 (cancelling sum);
// numerator f32; 8-deep load ILP (kept from R18 — mechanism-neutral).
// ---------------------------------------------------------------------------
__global__ __launch_bounds__(256) void gather_both(
    const int2* __restrict__ srtT, const int* __restrict__ ptr_r,
    const float* __restrict__ s_msg, float* __restrict__ msg_tgt,
    const int2* __restrict__ srtS, const int* __restrict__ ptr_c,
    const float* __restrict__ t_msg, float* __restrict__ msg_src,
    const double* __restrict__ es_d, const double* __restrict__ et_d)
{
    const int gw   = (blockIdx.x * blockDim.x + threadIdx.x) >> 6;
    const int lane = threadIdx.x & 63;

    const int2* srt; const int* ptr; const float* min_; float* out;
    const double* other_d; double base; int row;
    if (gw < N_TGT) {
        srt = srtT; ptr = ptr_r; min_ = s_msg; out = msg_tgt;
        other_d = es_d; row = gw; base = et_d[row];
    } else {
        row = gw - N_TGT;
        if (row >= N_SRC) return;
        srt = srtS; ptr = ptr_c; min_ = t_msg; out = msg_src;
        other_d = et_d; base = es_d[row];
    }

    const int b = ptr[row], e = ptr[row + 1];
    double den = 0.0;
    float a0 = 0.f, a1 = 0.f, a2 = 0.f, a3 = 0.f;

    for (int j0 = b; j0 < e; j0 += 64) {
        const int m = e - j0;
        int oidx = 0; double v = 0.0; float wf = 0.f;
        if (lane < m) {
            const int2 pay = srt[j0 + lane];
            oidx = pay.x;
            const float nb = __int_as_float(pay.y);
            const double sv = base + other_d[oidx];
            v = (sv >= 0.0) ? sv : NEG * sv;
            wf = (float)(v * (double)nb);
        }
        den += v;

        const int cnt = m < 64 ? m : 64;
        int j = 0;
        for (; j + 7 < cnt; j += 8) {
            const int   c0_ = __shfl(oidx, j);     const float w0 = __shfl(wf, j);
            const int   c1_ = __shfl(oidx, j + 1); const float w1 = __shfl(wf, j + 1);
            const int   c2_ = __shfl(oidx, j + 2); const float w2 = __shfl(wf, j + 2);
            const int   c3_ = __shfl(oidx, j + 3); const float w3 = __shfl(wf, j + 3);
            const int   c4_ = __shfl(oidx, j + 4); const float w4 = __shfl(wf, j + 4);
            const int   c5_ = __shfl(oidx, j + 5); const float w5 = __shfl(wf, j + 5);
            const int   c6_ = __shfl(oidx, j + 6); const float w6 = __shfl(wf, j + 6);
            const int   c7_ = __shfl(oidx, j + 7); const float w7 = __shfl(wf, j + 7);
            const float m0 = min_[(size_t)c0_ * 64 + lane];
            const float m1 = min_[(size_t)c1_ * 64 + lane];
            const float m2 = min_[(size_t)c2_ * 64 + lane];
            const float m3 = min_[(size_t)c3_ * 64 + lane];
            const float m4 = min_[(size_t)c4_ * 64 + lane];
            const float m5 = min_[(size_t)c5_ * 64 + lane];
            const float m6 = min_[(size_t)c6_ * 64 + lane];
            const float m7 = min_[(size_t)c7_ * 64 + lane];
            a0 = fmaf(w0, m0, a0); a1 = fmaf(w1, m1, a1);
            a2 = fmaf(w2, m2, a2); a3 = fmaf(w3, m3, a3);
            a0 = fmaf(w4, m4, a0); a1 = fmaf(w5, m5, a1);
            a2 = fmaf(w6, m6, a2); a3 = fmaf(w7, m7, a3);
        }
        for (; j + 3 < cnt; j += 4) {
            const int   c0_ = __shfl(oidx, j);     const float w0 = __shfl(wf, j);
            const int   c1_ = __shfl(oidx, j + 1); const float w1 = __shfl(wf, j + 1);
            const int   c2_ = __shfl(oidx, j + 2); const float w2 = __shfl(wf, j + 2);
            const int   c3_ = __shfl(oidx, j + 3); const float w3 = __shfl(wf, j + 3);
            a0 = fmaf(w0, min_[(size_t)c0_ * 64 + lane], a0);
            a1 = fmaf(w1, min_[(size_t)c1_ * 64 + lane], a1);
            a2 = fmaf(w2, min_[(size_t)c2_ * 64 + lane], a2);
            a3 = fmaf(w3, min_[(size_t)c3_ * 64 + lane], a3);
        }
        for (; j < cnt; ++j) {
            const int   c = __shfl(oidx, j);
            const float w = __shfl(wf, j);
            a0 = fmaf(w, min_[(size_t)c * 64 + lane], a0);
        }
    }
    #pragma unroll
    for (int s = 32; s; s >>= 1) den += __shfl_xor(den, s);
    const double inv = (den != 0.0) ? 1.0 / den : 0.0;
    const double acc = (double)((a0 + a1) + (a2 + a3));
    out[(size_t)row * 64 + lane] = (float)(acc * inv);
}

// ===========================================================================
extern "C" void kernel_launch(void* const* d_in, const int* in_sizes, int n_in,
                              void* d_out, int out_size, void* d_ws, size_t ws_size,
                              hipStream_t stream)
{
    const float* x_source = (const float*)d_in[0];
    const float* x_target = (const float*)d_in[1];
    const float* w_s      = (const float*)d_in[2];
    const float* w_t      = (const float*)d_in[3];
    const float* att      = (const float*)d_in[4];
    const float* nbhd     = (const float*)d_in[5];
    const int*   rows     = (const int*)d_in[6];
    const int*   cols     = (const int*)d_in[7];

    float* out     = (float*)d_out;
    float* msg_src = out;                       // (N_SRC, 64)
    float* msg_tgt = out + (size_t)N_SRC * 64;  // (N_TGT, 64)

    char* ws = (char*)d_ws;
    // byte layout: total 65,400,016 B
    float*    s_msg  = (float*)   (ws + 0);           // 25,600,000
    float*    t_msg  = (float*)   (ws + 25600000);    // 12,800,000
    double*   es_d   = (double*)  (ws + 38400000);    //    800,000
    double*   et_d   = (double*)  (ws + 39200000);    //    400,000
    int*      cnt_r  = (int*)     (ws + 39600000);    //    200,000
    int*      cnt_c  = (int*)     (ws + 39800000);    //    400,000
    int*      ptr_r  = (int*)     (ws + 40200000);    //    200,004
    int*      ptr_c  = (int*)     (ws + 40400004);    //    400,004 (+8 pad)
    unsigned* packT  = (unsigned*)(ws + 40800016);    //  4,000,000
    unsigned* packC  = (unsigned*)(ws + 44800016);    //  4,000,000
    unsigned long long* srtT = (unsigned long long*)(ws + 48800016); // 8,000,000
    unsigned long long* srtS = (unsigned long long*)(ws + 56800016); // 8,000,000

    hipMemsetAsync(ws + 39600000, 0, 600000, stream);  // cnt_r + cnt_c

    fused_gemm_hist<<<NHIST + GBLK, 256, 0, stream>>>(
        x_source, x_target, w_s, w_t, att,
        s_msg, t_msg, es_d, et_d,
        rows, cols, cnt_r, cnt_c, packT, packC);

    scan_two<<<2, 1024, 0, stream>>>(cnt_r, cnt_c, ptr_r, ptr_c);
    scatter_part<<<2048, 256, 0, stream>>>(
        packT, packC, nbhd, ptr_r, ptr_c, srtT, srtS);

    gather_both<<<(N_TGT + N_SRC + 3) / 4, 256, 0, stream>>>(
        (const int2*)srtT, ptr_r, s_msg, msg_tgt,
        (const int2*)srtS, ptr_c, t_msg, msg_src, es_d, et_d);
}

// Round 20
// 278.792 us; speedup vs baseline: 1.0855x; 1.0038x over previous
//
#include <hip/hip_runtime.h>

#define N_SRC   100000
#define N_TGT   50000
#define N_EDGES 1000000
#define NEG     0.2
#define NXCD    8
#define TPART   (N_TGT / NXCD)   // 6250
#define SPART   (N_SRC / NXCD)   // 12500

#define GBLK_S  1563             // ceil(N_SRC/64)
#define GBLK_T  782              // ceil(N_TGT/64)
#define GBLK    (GBLK_S + GBLK_T)          // 2345 gemm blocks
#define NHIST   640              // hist blocks, grid-stride, dispatched FIRST

// ===========================================================================
// R20: scatter partition loop 4x-unrolled (R19 residual: serial latency chain
// load->ptr-lookup->store, ~15 dependent iters/thread, VALUBusy ~0.2%).
// Single change vs R19 (279.9 us best) for clean attribution.
// ===========================================================================

// ---------------------------------------------------------------------------
#define XS2 65
__global__ __launch_bounds__(256) void fused_gemm_hist(
    const float* __restrict__ x_source, const float* __restrict__ x_target,
    const float* __restrict__ w_s, const float* __restrict__ w_t,
    const float* __restrict__ att,
    float* __restrict__ s_msg, float* __restrict__ t_msg,
    double* __restrict__ es_d, double* __restrict__ et_d,
    const int* __restrict__ rows, const int* __restrict__ cols,
    int* __restrict__ cnt_r, int* __restrict__ cnt_c,
    unsigned* __restrict__ packT, unsigned* __restrict__ packC)
{
    __shared__ float xs[64 * XS2];         // 16.6 KB
    __shared__ double eds[4][64];          //  2.0 KB
    const int tid = threadIdx.x;

    if (blockIdx.x < NHIST) {
        // ------- hist branch: dispatched first, grid-stride, 4x unrolled ------
        const int S = NHIST * 256;
        int i = blockIdx.x * 256 + tid;
        for (; i + 3 * S < N_EDGES; i += 4 * S) {
            const unsigned r0 = rows[i],         c0_ = cols[i];
            const unsigned r1 = rows[i + S],     c1_ = cols[i + S];
            const unsigned r2 = rows[i + 2 * S], c2_ = cols[i + 2 * S];
            const unsigned r3 = rows[i + 3 * S], c3_ = cols[i + 3 * S];
            const unsigned kr0 = atomicAdd(&cnt_r[r0], 1);
            const unsigned kc0 = atomicAdd(&cnt_c[c0_], 1);
            const unsigned kr1 = atomicAdd(&cnt_r[r1], 1);
            const unsigned kc1 = atomicAdd(&cnt_c[c1_], 1);
            const unsigned kr2 = atomicAdd(&cnt_r[r2], 1);
            const unsigned kc2 = atomicAdd(&cnt_c[c2_], 1);
            const unsigned kr3 = atomicAdd(&cnt_r[r3], 1);
            const unsigned kc3 = atomicAdd(&cnt_c[c3_], 1);
            packT[i]         = r0 | (kr0 << 16); packC[i]         = c0_ | (kc0 << 17);
            packT[i + S]     = r1 | (kr1 << 16); packC[i + S]     = c1_ | (kc1 << 17);
            packT[i + 2 * S] = r2 | (kr2 << 16); packC[i + 2 * S] = c2_ | (kc2 << 17);
            packT[i + 3 * S] = r3 | (kr3 << 16); packC[i + 3 * S] = c3_ | (kc3 << 17);
        }
        for (; i < N_EDGES; i += S) {
            const unsigned r = rows[i], c = cols[i];
            packT[i] = r | ((unsigned)atomicAdd(&cnt_r[r], 1) << 16);
            packC[i] = c | ((unsigned)atomicAdd(&cnt_c[c], 1) << 17);
        }
        return;
    }

    // ---------------- gemm branch ----------------
    const int gi = blockIdx.x - NHIST;

    const float* x; const float* w; int att_off, nrows, bblk;
    float* msg; double* evec;
    if (gi < GBLK_S) { x = x_source; w = w_s; att_off = 0;  nrows = N_SRC;
                       msg = s_msg;  evec = es_d; bblk = gi; }
    else             { x = x_target; w = w_t; att_off = 64; nrows = N_TGT;
                       msg = t_msg;  evec = et_d; bblk = gi - GBLK_S; }

    const int lane = tid & 63;
    const int part = tid >> 6;
    const int c0   = __builtin_amdgcn_readfirstlane(part << 4);
    const int row0 = bblk * 64;
    const int row  = row0 + lane;
    const bool act = row < nrows;

    float acc[16];
    #pragma unroll
    for (int c = 0; c < 16; ++c) acc[c] = 0.f;

    const int xbase = lane * XS2;

    // ---- stage half0 ----
    #pragma unroll
    for (int it = 0; it < 4; ++it) {
        const int fid = tid + it * 256;
        const int r = fid >> 4, q = fid & 15;
        if (row0 + r < nrows) {
            const float4 v = *(const float4*)(x + (size_t)(row0 + r) * 128 + 4 * q);
            float* d = &xs[r * XS2 + 4 * q];
            d[0] = v.x; d[1] = v.y; d[2] = v.z; d[3] = v.w;
        }
    }
    __syncthreads();

    // ---- issue half1 loads (in flight during half0 compute) ----
    float4 pre[4];
    #pragma unroll
    for (int it = 0; it < 4; ++it) {
        const int fid = tid + it * 256;
        const int r = fid >> 4, q = fid & 15;
        pre[it] = (row0 + r < nrows)
            ? *(const float4*)(x + (size_t)(row0 + r) * 128 + 64 + 4 * q)
            : make_float4(0.f, 0.f, 0.f, 0.f);
    }

    // ---- compute half0 ----
    for (int kc = 0; kc < 64; kc += 16) {
        #pragma unroll
        for (int kk = 0; kk < 16; ++kk) {
            const float xk = xs[xbase + kc + kk];
            const float* wr = w + (size_t)(kc + kk) * 64 + c0;   // scalar addr
            #pragma unroll
            for (int c = 0; c < 16; ++c)
                acc[c] = fmaf(xk, wr[c], acc[c]);
        }
    }
    __syncthreads();

    // ---- write half1 to LDS ----
    #pragma unroll
    for (int it = 0; it < 4; ++it) {
        const int fid = tid + it * 256;
        const int r = fid >> 4, q = fid & 15;
        float* d = &xs[r * XS2 + 4 * q];
        d[0] = pre[it].x; d[1] = pre[it].y; d[2] = pre[it].z; d[3] = pre[it].w;
    }
    __syncthreads();

    // ---- compute half1 ----
    for (int kc = 0; kc < 64; kc += 16) {
        #pragma unroll
        for (int kk = 0; kk < 16; ++kk) {
            const float xk = xs[xbase + kc + kk];
            const float* wr = w + (size_t)(64 + kc + kk) * 64 + c0;
            #pragma unroll
            for (int c = 0; c < 16; ++c)
                acc[c] = fmaf(xk, wr[c], acc[c]);
        }
    }

    double e = 0.0;
    #pragma unroll
    for (int c = 0; c < 16; ++c)
        e += (double)acc[c] * (double)att[att_off + c0 + c];
    eds[part][lane] = e;
    __syncthreads();
    if (part == 0 && act)
        evec[row] = eds[0][lane] + eds[1][lane] + eds[2][lane] + eds[3][lane];

    if (act) {
        float* mo = msg + (size_t)row * 64 + c0;
        #pragma unroll
        for (int q = 0; q < 4; ++q)
            *(float4*)(mo + 4 * q) = *(float4*)(acc + 4 * q);
    }
}

// ---------------------------------------------------------------------------
// Exclusive scan, tiled + coalesced. block 0 -> rows (N_TGT), 1 -> cols (N_SRC).
// ---------------------------------------------------------------------------
__global__ __launch_bounds__(1024) void scan_two(
    const int* __restrict__ cnt_r, const int* __restrict__ cnt_c,
    int* __restrict__ ptr_r, int* __restrict__ ptr_c)
{
    const int n    = blockIdx.x ? N_SRC : N_TGT;
    const int* cnt = blockIdx.x ? cnt_c : cnt_r;
    int* ptr       = blockIdx.x ? ptr_c : ptr_r;
    const int tid  = threadIdx.x;
    const int lane = tid & 63, wid = tid >> 6;

    __shared__ int wsum[16];
    __shared__ int s_carry;
    if (tid == 0) s_carry = 0;
    __syncthreads();

    for (int base = 0; base < n; base += 4096) {
        const int idx = base + tid * 4;
        int4 v = make_int4(0, 0, 0, 0);
        if (idx + 3 < n) {
            v = *(const int4*)(cnt + idx);
        } else if (idx < n) {
            v.x = cnt[idx];
            if (idx + 1 < n) v.y = cnt[idx + 1];
            if (idx + 2 < n) v.z = cnt[idx + 2];
        }
        const int s = v.x + v.y + v.z + v.w;

        int p = s;
        #pragma unroll
        for (int d = 1; d < 64; d <<= 1) {
            int t = __shfl_up(p, d);
            if (lane >= d) p += t;
        }
        if (lane == 63) wsum[wid] = p;
        __syncthreads();
        if (tid == 0) {
            int a = 0;
            #pragma unroll
            for (int i = 0; i < 16; ++i) { int t = wsum[i]; wsum[i] = a; a += t; }
        }
        __syncthreads();

        int run = s_carry + wsum[wid] + (p - s);
        if (idx     < n) ptr[idx]     = run; run += v.x;
        if (idx + 1 < n) ptr[idx + 1] = run; run += v.y;
        if (idx + 2 < n) ptr[idx + 2] = run; run += v.z;
        if (idx + 3 < n) ptr[idx + 3] = run; run += v.w;

        __syncthreads();
        if (tid == 1023) s_carry = run;
        __syncthreads();
    }
    if (tid == 0) ptr[n] = s_carry;
}

// ---------------------------------------------------------------------------
// Scatter, XCD-partitioned (R8) + atomic-free (R12) + packed (R17) + 4x
// unrolled (R20): 4 independent load->ptr-lookup->store chains in flight.
// ---------------------------------------------------------------------------
__global__ __launch_bounds__(256) void scatter_part(
    const unsigned* __restrict__ packT, const unsigned* __restrict__ packC,
    const float* __restrict__ nbhd,
    const int* __restrict__ ptr_r, const int* __restrict__ ptr_c,
    unsigned long long* __restrict__ srtT, unsigned long long* __restrict__ srtS)
{
    const int xcd  = blockIdx.x & (NXCD - 1);
    const int ibx  = blockIdx.x >> 3;
    const int step = (gridDim.x >> 3) * blockDim.x;
    const unsigned lo_r = xcd * TPART, lo_c = xcd * SPART;

    int i = ibx * blockDim.x + threadIdx.x;
    for (; i + 3 * step < N_EDGES; i += 4 * step) {
        const unsigned pT0 = packT[i],            pC0 = packC[i];
        const unsigned pT1 = packT[i + step],     pC1 = packC[i + step];
        const unsigned pT2 = packT[i + 2 * step], pC2 = packC[i + 2 * step];
        const unsigned pT3 = packT[i + 3 * step], pC3 = packC[i + 3 * step];
        const float    nf0 = nbhd[i],             nf1 = nbhd[i + step];
        const float    nf2 = nbhd[i + 2 * step],  nf3 = nbhd[i + 3 * step];

        const unsigned r0 = pT0 & 0xFFFFu, kr0 = pT0 >> 16;
        const unsigned r1 = pT1 & 0xFFFFu, kr1 = pT1 >> 16;
        const unsigned r2 = pT2 & 0xFFFFu, kr2 = pT2 >> 16;
        const unsigned r3 = pT3 & 0xFFFFu, kr3 = pT3 >> 16;
        const unsigned c0 = pC0 & 0x1FFFFu, kc0 = pC0 >> 17;
        const unsigned c1 = pC1 & 0x1FFFFu, kc1 = pC1 >> 17;
        const unsigned c2 = pC2 & 0x1FFFFu, kc2 = pC2 >> 17;
        const unsigned c3 = pC3 & 0x1FFFFu, kc3 = pC3 >> 17;

        const bool mr0 = (r0 - lo_r) < TPART, mc0 = (c0 - lo_c) < SPART;
        const bool mr1 = (r1 - lo_r) < TPART, mc1 = (c1 - lo_c) < SPART;
        const bool mr2 = (r2 - lo_r) < TPART, mc2 = (c2 - lo_c) < SPART;
        const bool mr3 = (r3 - lo_r) < TPART, mc3 = (c3 - lo_c) < SPART;

        const unsigned long long nb0 = (unsigned long long)(unsigned)__float_as_int(nf0) << 32;
        const unsigned long long nb1 = (unsigned long long)(unsigned)__float_as_int(nf1) << 32;
        const unsigned long long nb2 = (unsigned long long)(unsigned)__float_as_int(nf2) << 32;
        const unsigned long long nb3 = (unsigned long long)(unsigned)__float_as_int(nf3) << 32;

        if (mr0) srtT[ptr_r[r0] + kr0] = nb0 | c0;
        if (mr1) srtT[ptr_r[r1] + kr1] = nb1 | c1;
        if (mr2) srtT[ptr_r[r2] + kr2] = nb2 | c2;
        if (mr3) srtT[ptr_r[r3] + kr3] = nb3 | c3;
        if (mc0) srtS[ptr_c[c0] + kc0] = nb0 | r0;
        if (mc1) srtS[ptr_c[c1] + kc1] = nb1 | r1;
        if (mc2) srtS[ptr_c[c2] + kc2] = nb2 | r2;
        if (mc3) srtS[ptr_c[c3] + kc3] = nb3 | r3;
    }
    for (; i < N_EDGES; i += step) {
        const unsigned pT = packT[i], pC = packC[i];
        const unsigned r = pT & 0xFFFFu,  kr = pT >> 16;
        const unsigned c = pC & 0x1FFFFu, kc = pC >> 17;
        const bool mr = (r - lo_r) < TPART;
        const bool mc = (c - lo_c) < SPART;
        if (!(mr | mc)) continue;
        const unsigned long long nb =
            (unsigned long long)(unsigned)__float_as_int(nbhd[i]) << 32;
        if (mr) srtT[ptr_r[r] + kr] = nb | c;
        if (mc) srtS[ptr_c[c] + kc] = nb | r;
    }
}

// ---------------------------------------------------------------------------
// Gather: one wave per output row, lane = feature. den f64 (cancelling sum);
// numerator f32; 8-deep load ILP.
// ---------------------------------------------------------------------------
__global__ __launch_bounds__(256) void gather_both(
    const int2* __restrict__ srtT, const int* __restrict__ ptr_r,
    const float* __restrict__ s_msg, float* __restrict__ msg_tgt,
    const int2* __restrict__ srtS, const int* __restrict__ ptr_c,
    const float* __restrict__ t_msg, float* __restrict__ msg_src,
    const double* __restrict__ es_d, const double* __restrict__ et_d)
{
    const int gw   = (blockIdx.x * blockDim.x + threadIdx.x) >> 6;
    const int lane = threadIdx.x & 63;

    const int2* srt; const int* ptr; const float* min_; float* out;
    const double* other_d; double base; int row;
    if (gw < N_TGT) {
        srt = srtT; ptr = ptr_r; min_ = s_msg; out = msg_tgt;
        other_d = es_d; row = gw; base = et_d[row];
    } else {
        row = gw - N_TGT;
        if (row >= N_SRC) return;
        srt = srtS; ptr = ptr_c; min_ = t_msg; out = msg_src;
        other_d = et_d; base = es_d[row];
    }

    const int b = ptr[row], e = ptr[row + 1];
    double den = 0.0;
    float a0 = 0.f, a1 = 0.f, a2 = 0.f, a3 = 0.f;

    for (int j0 = b; j0 < e; j0 += 64) {
        const int m = e - j0;
        int oidx = 0; double v = 0.0; float wf = 0.f;
        if (lane < m) {
            const int2 pay = srt[j0 + lane];
            oidx = pay.x;
            const float nb = __int_as_float(pay.y);
            const double sv = base + other_d[oidx];
            v = (sv >= 0.0) ? sv : NEG * sv;
            wf = (float)(v * (double)nb);
        }
        den += v;

        const int cnt = m < 64 ? m : 64;
        int j = 0;
        for (; j + 7 < cnt; j += 8) {
            const int   c0_ = __shfl(oidx, j);     const float w0 = __shfl(wf, j);
            const int   c1_ = __shfl(oidx, j + 1); const float w1 = __shfl(wf, j + 1);
            const int   c2_ = __shfl(oidx, j + 2); const float w2 = __shfl(wf, j + 2);
            const int   c3_ = __shfl(oidx, j + 3); const float w3 = __shfl(wf, j + 3);
            const int   c4_ = __shfl(oidx, j + 4); const float w4 = __shfl(wf, j + 4);
            const int   c5_ = __shfl(oidx, j + 5); const float w5 = __shfl(wf, j + 5);
            const int   c6_ = __shfl(oidx, j + 6); const float w6 = __shfl(wf, j + 6);
            const int   c7_ = __shfl(oidx, j + 7); const float w7 = __shfl(wf, j + 7);
            const float m0 = min_[(size_t)c0_ * 64 + lane];
            const float m1 = min_[(size_t)c1_ * 64 + lane];
            const float m2 = min_[(size_t)c2_ * 64 + lane];
            const float m3 = min_[(size_t)c3_ * 64 + lane];
            const float m4 = min_[(size_t)c4_ * 64 + lane];
            const float m5 = min_[(size_t)c5_ * 64 + lane];
            const float m6 = min_[(size_t)c6_ * 64 + lane];
            const float m7 = min_[(size_t)c7_ * 64 + lane];
            a0 = fmaf(w0, m0, a0); a1 = fmaf(w1, m1, a1);
            a2 = fmaf(w2, m2, a2); a3 = fmaf(w3, m3, a3);
            a0 = fmaf(w4, m4, a0); a1 = fmaf(w5, m5, a1);
            a2 = fmaf(w6, m6, a2); a3 = fmaf(w7, m7, a3);
        }
        for (; j + 3 < cnt; j += 4) {
            const int   c0_ = __shfl(oidx, j);     const float w0 = __shfl(wf, j);
            const int   c1_ = __shfl(oidx, j + 1); const float w1 = __shfl(wf, j + 1);
            const int   c2_ = __shfl(oidx, j + 2); const float w2 = __shfl(wf, j + 2);
            const int   c3_ = __shfl(oidx, j + 3); const float w3 = __shfl(wf, j + 3);
            a0 = fmaf(w0, min_[(size_t)c0_ * 64 + lane], a0);
            a1 = fmaf(w1, min_[(size_t)c1_ * 64 + lane], a1);
            a2 = fmaf(w2, min_[(size_t)c2_ * 64 + lane], a2);
            a3 = fmaf(w3, min_[(size_t)c3_ * 64 + lane], a3);
        }
        for (; j < cnt; ++j) {
            const int   c = __shfl(oidx, j);
            const float w = __shfl(wf, j);
            a0 = fmaf(w, min_[(size_t)c * 64 + lane], a0);
        }
    }
    #pragma unroll
    for (int s = 32; s; s >>= 1) den += __shfl_xor(den, s);
    const double inv = (den != 0.0) ? 1.0 / den : 0.0;
    const double acc = (double)((a0 + a1) + (a2 + a3));
    out[(size_t)row * 64 + lane] = (float)(acc * inv);
}

// ===========================================================================
extern "C" void kernel_launch(void* const* d_in, const int* in_sizes, int n_in,
                              void* d_out, int out_size, void* d_ws, size_t ws_size,
                              hipStream_t stream)
{
    const float* x_source = (const float*)d_in[0];
    const float* x_target = (const float*)d_in[1];
    const float* w_s      = (const float*)d_in[2];
    const float* w_t      = (const float*)d_in[3];
    const float* att      = (const float*)d_in[4];
    const float* nbhd     = (const float*)d_in[5];
    const int*   rows     = (const int*)d_in[6];
    const int*   cols     = (const int*)d_in[7];

    float* out     = (float*)d_out;
    float* msg_src = out;                       // (N_SRC, 64)
    float* msg_tgt = out + (size_t)N_SRC * 64;  // (N_TGT, 64)

    char* ws = (char*)d_ws;
    // byte layout: total 65,400,016 B
    float*    s_msg  = (float*)   (ws + 0);           // 25,600,000
    float*    t_msg  = (float*)   (ws + 25600000);    // 12,800,000
    double*   es_d   = (double*)  (ws + 38400000);    //    800,000
    double*   et_d   = (double*)  (ws + 39200000);    //    400,000
    int*      cnt_r  = (int*)     (ws + 39600000);    //    200,000
    int*      cnt_c  = (int*)     (ws + 39800000);    //    400,000
    int*      ptr_r  = (int*)     (ws + 40200000);    //    200,004
    int*      ptr_c  = (int*)     (ws + 40400004);    //    400,004 (+8 pad)
    unsigned* packT  = (unsigned*)(ws + 40800016);    //  4,000,000
    unsigned* packC  = (unsigned*)(ws + 44800016);    //  4,000,000
    unsigned long long* srtT = (unsigned long long*)(ws + 48800016); // 8,000,000
    unsigned long long* srtS = (unsigned long long*)(ws + 56800016); // 8,000,000

    hipMemsetAsync(ws + 39600000, 0, 600000, stream);  // cnt_r + cnt_c

    fused_gemm_hist<<<NHIST + GBLK, 256, 0, stream>>>(
        x_source, x_target, w_s, w_t, att,
        s_msg, t_msg, es_d, et_d,
        rows, cols, cnt_r, cnt_c, packT, packC);

    scan_two<<<2, 1024, 0, stream>>>(cnt_r, cnt_c, ptr_r, ptr_c);
    scatter_part<<<2048, 256, 0, stream>>>(
        packT, packC, nbhd, ptr_r, ptr_c, srtT, srtS);

    gather_both<<<(N_TGT + N_SRC + 3) / 4, 256, 0, stream>>>(
        (const int2*)srtT, ptr_r, s_msg, msg_tgt,
        (const int2*)srtS, ptr_c, t_msg, msg_src, es_d, et_d);
}